// Round 2
// baseline (517.401 us; speedup 1.0000x reference)
//
#include <hip/hip_runtime.h>

#define D_MODEL 1024
#define NTOK    4096
#define SEQ     2048
#define NH      16
#define HD      64

typedef __bf16 bh8  __attribute__((ext_vector_type(8)));
typedef float  f32x4 __attribute__((ext_vector_type(4)));
struct __align__(8) us4s { unsigned short x, y, z, w; };

__device__ __forceinline__ unsigned short f2bf(float f) {       // RNE float->bf16
  unsigned int u = __float_as_uint(f);
  u += 0x7fffu + ((u >> 16) & 1u);
  return (unsigned short)(u >> 16);
}
__device__ __forceinline__ float bf2f(unsigned short h) {
  return __uint_as_float(((unsigned int)h) << 16);
}
__device__ __forceinline__ unsigned short i2bf(int v) {         // exact for |v|<=255
  unsigned int u = __float_as_uint((float)v);
  return (unsigned short)(u >> 16);
}

// ---------------------------------------------------------------------------
// GEMM: C[m][n] = sum_k A[m][k]*B[n][k], K=1024, tiles 128x128x64, 4 waves.
// MODE 0: A=x(int32) B=w(int32), epi: hi/lo bf16 -> [b,h,s,d] layout (q or k)
// MODE 2: A=wv(int32,M=1024 feats) B=x(int32,N=4096 toks), epi: bf16 -> [b,h,d,s]
// MODE 3: A=o_q(bf16) B=wo(int32), epi: fp32 out
// LDS XOR swizzle: 16B chunk c stored at c^(row&7); same on read -> conflict-free.
// ---------------------------------------------------------------------------
template <int MODE>
__launch_bounds__(256, 2)
__global__ void gemm_k(const void* __restrict__ Ap, const int* __restrict__ Bp,
                       const float* __restrict__ sRow, const float* __restrict__ sCol,
                       const float* __restrict__ bias,
                       unsigned short* __restrict__ o1, unsigned short* __restrict__ o2,
                       float* __restrict__ outF)
{
  __shared__ __align__(16) unsigned short As[128 * 64];
  __shared__ __align__(16) unsigned short Bs[128 * 64];
  const int t  = threadIdx.x;
  const int m0 = blockIdx.y * 128, n0 = blockIdx.x * 128;
  const int wid = t >> 6, lane = t & 63, g = lane >> 4, li = lane & 15;
  const int wm = wid >> 1, wn = wid & 1;

  f32x4 acc[4][4];
#pragma unroll
  for (int i = 0; i < 4; ++i)
#pragma unroll
    for (int j = 0; j < 4; ++j) acc[i][j] = (f32x4)0.0f;

  for (int k0 = 0; k0 < 1024; k0 += 64) {
    __syncthreads();
    if (MODE == 3) {  // A already bf16: 128 rows x 64 cols x 2B = 1024 chunks
      const unsigned short* A16 = (const unsigned short*)Ap;
#pragma unroll
      for (int j = 0; j < 4; ++j) {
        int c16 = t + 256 * j;            // 1024 16B-chunks
        int r = c16 >> 3, c = c16 & 7;
        int4 w = *(const int4*)(A16 + (m0 + r) * 1024 + k0 + c * 8);
        *(int4*)((char*)As + r * 128 + ((c ^ (r & 7)) << 4)) = w;
      }
    } else {          // A int32 -> bf16 during staging
      const int* A32 = (const int*)Ap;
#pragma unroll
      for (int j = 0; j < 8; ++j) {
        int g4 = t + 256 * j;             // 2048 4-elem groups
        int r = g4 >> 4, cpos = g4 & 15;
        int4 w = *(const int4*)(A32 + (m0 + r) * 1024 + k0 + cpos * 4);
        us4s b4; b4.x = i2bf(w.x); b4.y = i2bf(w.y); b4.z = i2bf(w.z); b4.w = i2bf(w.w);
        *(us4s*)((char*)As + r * 128 + (((cpos >> 1) ^ (r & 7)) << 4) + ((cpos & 1) << 3)) = b4;
      }
    }
#pragma unroll
    for (int j = 0; j < 8; ++j) {         // B always int32
      int g4 = t + 256 * j;
      int r = g4 >> 4, cpos = g4 & 15;
      int4 w = *(const int4*)(Bp + (n0 + r) * 1024 + k0 + cpos * 4);
      us4s b4; b4.x = i2bf(w.x); b4.y = i2bf(w.y); b4.z = i2bf(w.z); b4.w = i2bf(w.w);
      *(us4s*)((char*)Bs + r * 128 + (((cpos >> 1) ^ (r & 7)) << 4) + ((cpos & 1) << 3)) = b4;
    }
    __syncthreads();
#pragma unroll
    for (int kc = 0; kc < 2; ++kc) {
      bh8 af[4], bfr[4];
#pragma unroll
      for (int mt = 0; mt < 4; ++mt) {
        int row = wm * 64 + mt * 16 + li;
        af[mt] = *(const bh8*)((const char*)As + row * 128 + ((((kc << 2) | g) ^ (row & 7)) << 4));
      }
#pragma unroll
      for (int nt = 0; nt < 4; ++nt) {
        int row = wn * 64 + nt * 16 + li;
        bfr[nt] = *(const bh8*)((const char*)Bs + row * 128 + ((((kc << 2) | g) ^ (row & 7)) << 4));
      }
#pragma unroll
      for (int mt = 0; mt < 4; ++mt)
#pragma unroll
        for (int nt = 0; nt < 4; ++nt)
          acc[mt][nt] = __builtin_amdgcn_mfma_f32_16x16x32_bf16(af[mt], bfr[nt], acc[mt][nt], 0, 0, 0);
    }
  }

  // epilogue: D tile layout col=lane&15, row=(lane>>4)*4+r
#pragma unroll
  for (int mt = 0; mt < 4; ++mt) {
#pragma unroll
    for (int nt = 0; nt < 4; ++nt) {
      const int nn = n0 + wn * 64 + nt * 16 + li;
#pragma unroll
      for (int r = 0; r < 4; ++r) {
        const int m = m0 + wm * 64 + mt * 16 + g * 4 + r;
        const float a = acc[mt][nt][r];
        float f;
        if (MODE == 2) f = a * (sRow[m] * sCol[nn]) + bias[m];
        else           f = a * (sRow[m] * sCol[nn]) + bias[nn];
        if (MODE == 0) {
          int bb = m >> 11, s = m & 2047, h = nn >> 6, d = nn & 63;
          size_t o = (((size_t)(bb * NH + h)) * SEQ + s) * HD + d;
          unsigned short hi = f2bf(f);
          unsigned short lo = f2bf(f - bf2f(hi));
          o1[o] = hi; o2[o] = lo;
        } else if (MODE == 2) {
          int h = m >> 6, d = m & 63, bb = nn >> 11, s = nn & 2047;
          size_t o = (((size_t)(bb * NH + h)) * HD + d) * SEQ + s;
          o1[o] = f2bf(f);
        } else {
          outF[(size_t)m * 1024 + nn] = f;
        }
      }
    }
  }
}

// ---------------------------------------------------------------------------
// Flash attention, swapped form: S^T = K·Q^T (softmax axis mostly lane-local),
// O^T = Vt·P^T.  4 waves x 16 q-rows, KBLK=64.  q,k hi/lo exact-ish scores.
// ---------------------------------------------------------------------------
__launch_bounds__(256, 2)
__global__ void attn_k(const unsigned short* __restrict__ qhi, const unsigned short* __restrict__ qlo,
                       const unsigned short* __restrict__ khi, const unsigned short* __restrict__ klo,
                       const unsigned short* __restrict__ vt, float* __restrict__ attn)
{
  __shared__ __align__(16) unsigned short khs[64 * 64], kls[64 * 64], vts[64 * 64];
  __shared__ __align__(16) unsigned short ps[4][16 * 64];
  const int t = threadIdx.x;
  const int w = t >> 6, lane = t & 63, g = lane >> 4, li = lane & 15;
  const int q0 = blockIdx.x * 64, h = blockIdx.y, b = blockIdx.z;
  const int bh = b * NH + h;

  const unsigned short* qrh = qhi + ((size_t)bh * SEQ + q0 + w * 16 + li) * HD;
  const unsigned short* qrl = qlo + ((size_t)bh * SEQ + q0 + w * 16 + li) * HD;
  bh8 qhf[2], qlf[2];
#pragma unroll
  for (int kc = 0; kc < 2; ++kc) {
    qhf[kc] = *(const bh8*)(qrh + kc * 32 + g * 8);
    qlf[kc] = *(const bh8*)(qrl + kc * 32 + g * 8);
  }
  const unsigned short* kb = khi + (size_t)bh * SEQ * HD;
  const unsigned short* lb = klo + (size_t)bh * SEQ * HD;
  const unsigned short* vb = vt  + (size_t)bh * HD * SEQ;

  float m_run = -INFINITY, l_run = 0.0f;
  f32x4 ot[4];
#pragma unroll
  for (int i = 0; i < 4; ++i) ot[i] = (f32x4)0.0f;

  for (int kk0 = 0; kk0 < SEQ; kk0 += 64) {
    __syncthreads();
#pragma unroll
    for (int j = 0; j < 2; ++j) {
      int c16 = t + 256 * j;
      int r = c16 >> 3, c = c16 & 7;
      int swz = (c ^ (r & 7)) << 4;
      *(int4*)((char*)khs + r * 128 + swz) = *(const int4*)(kb + (kk0 + r) * HD + c * 8);
      *(int4*)((char*)kls + r * 128 + swz) = *(const int4*)(lb + (kk0 + r) * HD + c * 8);
      *(int4*)((char*)vts + r * 128 + swz) = *(const int4*)(vb + (size_t)r * SEQ + kk0 + c * 8);
    }
    __syncthreads();

    f32x4 sa[4];
#pragma unroll
    for (int kt2 = 0; kt2 < 4; ++kt2) {
      sa[kt2] = (f32x4)0.0f;
      int row = kt2 * 16 + li, rx = row & 7;
#pragma unroll
      for (int kc = 0; kc < 2; ++kc) {
        bh8 kh = *(const bh8*)((const char*)khs + row * 128 + ((((kc << 2) | g) ^ rx) << 4));
        bh8 kl = *(const bh8*)((const char*)kls + row * 128 + ((((kc << 2) | g) ^ rx) << 4));
        sa[kt2] = __builtin_amdgcn_mfma_f32_16x16x32_bf16(kh, qhf[kc], sa[kt2], 0, 0, 0);
        sa[kt2] = __builtin_amdgcn_mfma_f32_16x16x32_bf16(kh, qlf[kc], sa[kt2], 0, 0, 0);
        sa[kt2] = __builtin_amdgcn_mfma_f32_16x16x32_bf16(kl, qhf[kc], sa[kt2], 0, 0, 0);
      }
    }
    // online softmax; lane holds 16 kk-values of one q-column (q = li)
    float p[4][4];
    float sm = -INFINITY;
#pragma unroll
    for (int kt2 = 0; kt2 < 4; ++kt2)
#pragma unroll
      for (int r = 0; r < 4; ++r) { p[kt2][r] = sa[kt2][r] * 0.125f; sm = fmaxf(sm, p[kt2][r]); }
    sm = fmaxf(sm, __shfl_xor(sm, 16));
    sm = fmaxf(sm, __shfl_xor(sm, 32));
    float mn = fmaxf(m_run, sm);
    float alpha = expf(m_run - mn);
    float ts = 0.0f;
#pragma unroll
    for (int kt2 = 0; kt2 < 4; ++kt2)
#pragma unroll
      for (int r = 0; r < 4; ++r) { p[kt2][r] = expf(p[kt2][r] - mn); ts += p[kt2][r]; }
    ts += __shfl_xor(ts, 16);
    ts += __shfl_xor(ts, 32);
    l_run = l_run * alpha + ts;
    m_run = mn;
#pragma unroll
    for (int i = 0; i < 4; ++i) ot[i] *= alpha;

    // P^T -> LDS (per-wave buffer), kk = kt2*16 + g*4 + r at row q=li
#pragma unroll
    for (int kt2 = 0; kt2 < 4; ++kt2) {
      us4s pk; pk.x = f2bf(p[kt2][0]); pk.y = f2bf(p[kt2][1]);
               pk.z = f2bf(p[kt2][2]); pk.w = f2bf(p[kt2][3]);
      int lchunk = (kt2 << 1) | (g >> 1);
      *(us4s*)((char*)ps[w] + li * 128 + ((lchunk ^ (li & 7)) << 4) + ((g & 1) << 3)) = pk;
    }
    asm volatile("s_waitcnt lgkmcnt(0)" ::: "memory");
    __builtin_amdgcn_sched_barrier(0);

#pragma unroll
    for (int kc2 = 0; kc2 < 2; ++kc2) {
      bh8 pf = *(const bh8*)((const char*)ps[w] + li * 128 + ((((kc2 << 2) | g) ^ (li & 7)) << 4));
#pragma unroll
      for (int dt = 0; dt < 4; ++dt) {
        int rowd = dt * 16 + li;
        bh8 vf = *(const bh8*)((const char*)vts + rowd * 128 + ((((kc2 << 2) | g) ^ (rowd & 7)) << 4));
        ot[dt] = __builtin_amdgcn_mfma_f32_16x16x32_bf16(vf, pf, ot[dt], 0, 0, 0);
      }
    }
  }

  const float inv = 1.0f / l_run;
  const int n = b * SEQ + q0 + w * 16 + li;
#pragma unroll
  for (int dt = 0; dt < 4; ++dt) {
    float4 o4;
    o4.x = ot[dt][0] * inv; o4.y = ot[dt][1] * inv;
    o4.z = ot[dt][2] * inv; o4.w = ot[dt][3] * inv;
    *(float4*)(attn + (size_t)n * D_MODEL + h * HD + dt * 16 + g * 4) = o4;
  }
}

// ---------------------------------------------------------------------------
// Per-token dynamic int8 quantization of attn rows.
// ---------------------------------------------------------------------------
__launch_bounds__(256)
__global__ void quant_k(const float* __restrict__ attn, unsigned short* __restrict__ oq,
                        float* __restrict__ osc)
{
  const int row = blockIdx.x, t = threadIdx.x;
  float4 v = *(const float4*)(attn + (size_t)row * D_MODEL + t * 4);
  float mx = fmaxf(fmaxf(fabsf(v.x), fabsf(v.y)), fmaxf(fabsf(v.z), fabsf(v.w)));
#pragma unroll
  for (int off = 1; off < 64; off <<= 1) mx = fmaxf(mx, __shfl_xor(mx, off));
  __shared__ float red[4];
  if ((t & 63) == 0) red[t >> 6] = mx;
  __syncthreads();
  mx = fmaxf(fmaxf(red[0], red[1]), fmaxf(red[2], red[3]));
  const float s = mx / 127.0f;
  if (t == 0) osc[row] = s;
  float q0 = fminf(fmaxf(rintf(v.x / s), -127.f), 127.f);
  float q1 = fminf(fmaxf(rintf(v.y / s), -127.f), 127.f);
  float q2 = fminf(fmaxf(rintf(v.z / s), -127.f), 127.f);
  float q3 = fminf(fmaxf(rintf(v.w / s), -127.f), 127.f);
  us4s r4; r4.x = f2bf(q0); r4.y = f2bf(q1); r4.z = f2bf(q2); r4.w = f2bf(q3);
  *(us4s*)(oq + (size_t)row * D_MODEL + t * 4) = r4;
}

// ---------------------------------------------------------------------------
extern "C" void kernel_launch(void* const* d_in, const int* in_sizes, int n_in,
                              void* d_out, int out_size, void* d_ws, size_t ws_size,
                              hipStream_t stream)
{
  const int*   x   = (const int*)d_in[0];
  const float* xs  = (const float*)d_in[1];
  const int*   wq  = (const int*)d_in[2];
  const float* wqs = (const float*)d_in[3];
  const float* bq  = (const float*)d_in[4];
  const int*   wk  = (const int*)d_in[5];
  const float* wks = (const float*)d_in[6];
  const float* bk  = (const float*)d_in[7];
  const int*   wv  = (const int*)d_in[8];
  const float* wvs = (const float*)d_in[9];
  const float* bv  = (const float*)d_in[10];
  const int*   wo  = (const int*)d_in[11];
  const float* wos = (const float*)d_in[12];
  const float* bo  = (const float*)d_in[13];
  float* out = (float*)d_out;

  char* ws = (char*)d_ws;
  const size_t EB = (size_t)NTOK * D_MODEL * 2;          // 8 MB per bf16 array
  unsigned short* qhi = (unsigned short*)(ws);
  unsigned short* qlo = (unsigned short*)(ws + EB);
  unsigned short* khi = (unsigned short*)(ws + 2 * EB);
  unsigned short* klo = (unsigned short*)(ws + 3 * EB);
  unsigned short* vtw = (unsigned short*)(ws + 4 * EB);
  float*          att = (float*)(ws + 5 * EB);           // 16 MB
  unsigned short* oq  = (unsigned short*)(ws + 5 * EB + (size_t)NTOK * D_MODEL * 4);
  float*          osc = (float*)(ws + 6 * EB + (size_t)NTOK * D_MODEL * 4);

  dim3 blk(256);
  gemm_k<0><<<dim3(8, 32), blk, 0, stream>>>(x, wq, xs, wqs, bq, qhi, qlo, nullptr);
  gemm_k<0><<<dim3(8, 32), blk, 0, stream>>>(x, wk, xs, wks, bk, khi, klo, nullptr);
  gemm_k<2><<<dim3(32, 8), blk, 0, stream>>>(wv, x, wvs, xs, bv, vtw, nullptr, nullptr);
  attn_k<<<dim3(32, NH, 2), blk, 0, stream>>>(qhi, qlo, khi, klo, vtw, att);
  quant_k<<<dim3(4096), blk, 0, stream>>>(att, oq, osc);
  gemm_k<3><<<dim3(8, 32), blk, 0, stream>>>(oq, wo, osc, wos, bo, nullptr, nullptr, out);
}

// Round 3
// 256.394 us; speedup vs baseline: 2.0180x; 2.0180x over previous
//
#include <hip/hip_runtime.h>

#define D_MODEL 1024
#define NTOK    4096
#define SEQ     2048
#define NH      16
#define HD      64

typedef __bf16 bh8  __attribute__((ext_vector_type(8)));
typedef __bf16 bf4  __attribute__((ext_vector_type(4)));
typedef float  f32x4 __attribute__((ext_vector_type(4)));
typedef int    i32x4 __attribute__((ext_vector_type(4)));

__device__ __forceinline__ unsigned short f2bf(float f) {       // RNE float->bf16
  unsigned int u = __float_as_uint(f);
  u += 0x7fffu + ((u >> 16) & 1u);
  return (unsigned short)(u >> 16);
}
__device__ __forceinline__ float bf2f(unsigned short h) {
  return __uint_as_float(((unsigned int)h) << 16);
}
__device__ __forceinline__ float exp2a(float x) {               // raw v_exp_f32 (2^x)
  float r; asm("v_exp_f32 %0, %1" : "=v"(r) : "v"(x)); return r;
}
// async global->LDS, 16B per lane; l must be wave-uniform (HW adds lane*16)
__device__ __forceinline__ void gl16(const void* g, void* l) {
  __builtin_amdgcn_global_load_lds((const __attribute__((address_space(1))) unsigned int*)g,
                                   (__attribute__((address_space(3))) unsigned int*)l, 16, 0, 0);
}

// ---------------------------------------------------------------------------
// Pack int32-held int8 -> int8, pre-swizzled for GEMM LDS tiles:
// within each 64-col group, 16B chunk c stored at c ^ ((m>>1)&3).
// ---------------------------------------------------------------------------
__device__ __forceinline__ void pack_row(const int* src, unsigned* dst, int m, int t) {
  int4 w = *(const int4*)(src + (size_t)m * 1024 + t * 4);
  unsigned p01 = __builtin_amdgcn_perm((unsigned)w.y, (unsigned)w.x, 0x00000400u);
  unsigned p23 = __builtin_amdgcn_perm((unsigned)w.w, (unsigned)w.z, 0x00000400u);
  unsigned r   = __builtin_amdgcn_perm(p23, p01, 0x05040100u);   // [x0,y0,z0,w0]
  int kg = t >> 4, c = (t >> 2) & 3, b4 = t & 3, sw = (m >> 1) & 3;
  dst[(size_t)m * 256 + kg * 16 + ((c ^ sw) << 2) + b4] = r;
}
__launch_bounds__(256)
__global__ void pack_x_k(const int* __restrict__ src, unsigned* __restrict__ dst) {
  pack_row(src, dst, blockIdx.x, threadIdx.x);
}
__launch_bounds__(256)
__global__ void pack_w_k(const int* __restrict__ s0, const int* __restrict__ s1,
                         const int* __restrict__ s2, const int* __restrict__ s3,
                         unsigned* __restrict__ d0, unsigned* __restrict__ d1,
                         unsigned* __restrict__ d2, unsigned* __restrict__ d3) {
  int wsel = blockIdx.x >> 10, m = blockIdx.x & 1023;
  const int* src = wsel == 0 ? s0 : wsel == 1 ? s1 : wsel == 2 ? s2 : s3;
  unsigned*  dst = wsel == 0 ? d0 : wsel == 1 ? d1 : wsel == 2 ? d2 : d3;
  pack_row(src, dst, m, threadIdx.x);
}

// ---------------------------------------------------------------------------
// int8 GEMM: C[m][n] = sum_k A[m][k]*B[n][k], K=1024, 128x128x64 tiles, 4 waves.
// A,B are packed pre-swizzled int8 -> staging is pure global_load_lds (dbuf).
// MODE 0: epi (acc*sA[m]*sB[n]+bias[n])*preScale -> hi/lo bf16 [b,h,s,d(swz?)]
// MODE 2: epi acc*sA[m]*sB[n]+bias[m] -> bf16 [b,h,d,s(swz)]  (V^T)
// MODE 3: epi acc*sA[m]*sB[n]+bias[n] -> fp32 out
// ---------------------------------------------------------------------------
template <int MODE>
__launch_bounds__(256, 2)
__global__ void gemm8_k(const signed char* __restrict__ Ap, const signed char* __restrict__ Bp,
                        const float* __restrict__ sA, const float* __restrict__ sB,
                        const float* __restrict__ bias, float preScale, int kswz,
                        unsigned short* __restrict__ o1, unsigned short* __restrict__ o2,
                        float* __restrict__ outF)
{
  __shared__ __align__(16) signed char As[2][8192];
  __shared__ __align__(16) signed char Bs[2][8192];
  const int t = threadIdx.x, wid = t >> 6, lane = t & 63, g = lane >> 4, li = lane & 15;
  const int wm = wid >> 1, wn = wid & 1;
  const int m0 = blockIdx.y * 128, n0 = blockIdx.x * 128;

  i32x4 acc[4][4];
#pragma unroll
  for (int i = 0; i < 4; ++i)
#pragma unroll
    for (int j = 0; j < 4; ++j) acc[i][j] = (i32x4){0, 0, 0, 0};

  const int unitBase = wid * 2;
  // prologue stage k0=0 into buffer 0
#pragma unroll
  for (int i = 0; i < 2; ++i) {
    int unit = (unitBase + i) * 64 + lane, r = unit >> 2, c = unit & 3;
    gl16(Ap + (size_t)(m0 + r) * 1024 + c * 16, (char*)As[0] + (unitBase + i) * 1024);
    gl16(Bp + (size_t)(n0 + r) * 1024 + c * 16, (char*)Bs[0] + (unitBase + i) * 1024);
  }
  __syncthreads();
  int p = 0;
#pragma unroll 1
  for (int ks = 0; ks < 16; ++ks) {
    if (ks < 15) {
      const int k0 = (ks + 1) * 64;
#pragma unroll
      for (int i = 0; i < 2; ++i) {
        int unit = (unitBase + i) * 64 + lane, r = unit >> 2, c = unit & 3;
        gl16(Ap + (size_t)(m0 + r) * 1024 + k0 + c * 16, (char*)As[p ^ 1] + (unitBase + i) * 1024);
        gl16(Bp + (size_t)(n0 + r) * 1024 + k0 + c * 16, (char*)Bs[p ^ 1] + (unitBase + i) * 1024);
      }
    }
    i32x4 af[4], bfr[4];
#pragma unroll
    for (int mt = 0; mt < 4; ++mt) {
      int row = wm * 64 + mt * 16 + li;
      af[mt] = *(const i32x4*)(As[p] + row * 64 + ((g ^ ((row >> 1) & 3)) << 4));
    }
#pragma unroll
    for (int nt = 0; nt < 4; ++nt) {
      int row = wn * 64 + nt * 16 + li;
      bfr[nt] = *(const i32x4*)(Bs[p] + row * 64 + ((g ^ ((row >> 1) & 3)) << 4));
    }
    __builtin_amdgcn_s_setprio(1);
#pragma unroll
    for (int mt = 0; mt < 4; ++mt)
#pragma unroll
      for (int nt = 0; nt < 4; ++nt)
        acc[mt][nt] = __builtin_amdgcn_mfma_i32_16x16x64_i8(af[mt], bfr[nt], acc[mt][nt], 0, 0, 0);
    __builtin_amdgcn_s_setprio(0);
    __syncthreads();
    p ^= 1;
  }

  // epilogue: D layout col=lane&15 (=n), row=(lane>>4)*4+r (=m)
#pragma unroll
  for (int mt = 0; mt < 4; ++mt) {
#pragma unroll
    for (int nt = 0; nt < 4; ++nt) {
      const int nn = n0 + wn * 64 + nt * 16 + li;
#pragma unroll
      for (int r = 0; r < 4; ++r) {
        const int m = m0 + wm * 64 + mt * 16 + g * 4 + r;
        const float a = (float)acc[mt][nt][r];          // exact: |acc| < 2^24
        if (MODE == 0) {
          float f = (a * (sA[m] * sB[nn]) + bias[nn]) * preScale;
          int bb = m >> 11, s = m & 2047, hh = nn >> 6, d = nn & 63;
          int dd = kswz ? ((((d >> 3) ^ (s & 7)) << 3) | (d & 7)) : d;
          size_t o = (((size_t)(bb * NH + hh)) * SEQ + s) * HD + dd;
          unsigned short hi = f2bf(f);
          unsigned short lo = f2bf(f - bf2f(hi));
          o1[o] = hi; o2[o] = lo;
        } else if (MODE == 2) {
          float f = a * (sA[m] * sB[nn]) + bias[m];
          int hh = m >> 6, d = m & 63, bb = nn >> 11, s = nn & 2047;
          int ss = (s & ~63) | (((((s >> 3) & 7) ^ (d & 7)) << 3) | (s & 7));
          size_t o = (((size_t)(bb * NH + hh)) * HD + d) * SEQ + ss;
          o1[o] = f2bf(f);
        } else {
          outF[(size_t)m * 1024 + nn] = a * (sA[m] * sB[nn]) + bias[nn];
        }
      }
    }
  }
}

// ---------------------------------------------------------------------------
// Flash attention, swapped form: S^T = K.Q^T, O^T = Vt.P^T. 4 waves x 16 q.
// Scores arrive pre-scaled by 0.125*log2e (folded into q GEMM) -> exp2 softmax.
// K/V buffers are pre-swizzled by their producer GEMMs -> global_load_lds direct.
// ---------------------------------------------------------------------------
__launch_bounds__(256, 2)
__global__ void attn_k(const unsigned short* __restrict__ qhi, const unsigned short* __restrict__ qlo,
                       const unsigned short* __restrict__ khi, const unsigned short* __restrict__ klo,
                       const unsigned short* __restrict__ vt, float* __restrict__ attn)
{
  __shared__ __align__(16) unsigned short khs[64 * 64], kls[64 * 64], vts[64 * 64];
  __shared__ __align__(16) unsigned short ps[4][16 * 64];
  const int t = threadIdx.x;
  const int w = t >> 6, lane = t & 63, g = lane >> 4, li = lane & 15;
  const int q0 = blockIdx.x * 64, h = blockIdx.y, b = blockIdx.z;
  const int bh = b * NH + h;

  const unsigned short* qrh = qhi + ((size_t)bh * SEQ + q0 + w * 16 + li) * HD;
  const unsigned short* qrl = qlo + ((size_t)bh * SEQ + q0 + w * 16 + li) * HD;
  bh8 qhf[2], qlf[2];
#pragma unroll
  for (int kc = 0; kc < 2; ++kc) {
    qhf[kc] = *(const bh8*)(qrh + kc * 32 + g * 8);
    qlf[kc] = *(const bh8*)(qrl + kc * 32 + g * 8);
  }
  const unsigned short* kb = khi + (size_t)bh * SEQ * HD;
  const unsigned short* lb = klo + (size_t)bh * SEQ * HD;
  const unsigned short* vb = vt  + (size_t)bh * HD * SEQ;

  float m_run = -INFINITY, l_run = 0.0f;
  f32x4 ot[4];
#pragma unroll
  for (int i = 0; i < 4; ++i) ot[i] = (f32x4)0.0f;

  for (int kk0 = 0; kk0 < SEQ; kk0 += 64) {
    __syncthreads();
#pragma unroll
    for (int i = 0; i < 2; ++i) {
      int unit = (w * 2 + i) * 64 + lane, r = unit >> 3, c = unit & 7;
      gl16(kb + (size_t)(kk0 + r) * 64 + c * 8, (char*)khs + (w * 2 + i) * 1024);
      gl16(lb + (size_t)(kk0 + r) * 64 + c * 8, (char*)kls + (w * 2 + i) * 1024);
      gl16(vb + (size_t)r * SEQ + kk0 + c * 8, (char*)vts + (w * 2 + i) * 1024);
    }
    __syncthreads();

    f32x4 sa[4];
#pragma unroll
    for (int kt2 = 0; kt2 < 4; ++kt2) {
      sa[kt2] = (f32x4)0.0f;
      int row = kt2 * 16 + li, rx = row & 7;
#pragma unroll
      for (int kc = 0; kc < 2; ++kc) {
        bh8 kh = *(const bh8*)((const char*)khs + row * 128 + ((((kc << 2) | g) ^ rx) << 4));
        bh8 kl = *(const bh8*)((const char*)kls + row * 128 + ((((kc << 2) | g) ^ rx) << 4));
        __builtin_amdgcn_s_setprio(1);
        sa[kt2] = __builtin_amdgcn_mfma_f32_16x16x32_bf16(kh, qhf[kc], sa[kt2], 0, 0, 0);
        sa[kt2] = __builtin_amdgcn_mfma_f32_16x16x32_bf16(kh, qlf[kc], sa[kt2], 0, 0, 0);
        sa[kt2] = __builtin_amdgcn_mfma_f32_16x16x32_bf16(kl, qhf[kc], sa[kt2], 0, 0, 0);
        __builtin_amdgcn_s_setprio(0);
      }
    }
    // online softmax in exp2 domain (scores pre-scaled); lane: 16 kk of q=li
    float p[4][4];
    float sm = -INFINITY;
#pragma unroll
    for (int kt2 = 0; kt2 < 4; ++kt2)
#pragma unroll
      for (int r = 0; r < 4; ++r) { p[kt2][r] = sa[kt2][r]; sm = fmaxf(sm, p[kt2][r]); }
    sm = fmaxf(sm, __shfl_xor(sm, 16));
    sm = fmaxf(sm, __shfl_xor(sm, 32));
    if (__any(sm > m_run + 11.0f)) {                 // defer-max: P bounded by 2^11
      float mn = fmaxf(m_run, sm);
      float alpha = exp2a(m_run - mn);
      l_run *= alpha;
#pragma unroll
      for (int i = 0; i < 4; ++i) ot[i] *= alpha;
      m_run = mn;
    }
    float ts = 0.0f;
#pragma unroll
    for (int kt2 = 0; kt2 < 4; ++kt2)
#pragma unroll
      for (int r = 0; r < 4; ++r) { float e = exp2a(p[kt2][r] - m_run); p[kt2][r] = e; ts += e; }
    ts += __shfl_xor(ts, 16);
    ts += __shfl_xor(ts, 32);
    l_run += ts;

    // P^T -> LDS (per-wave), kk = kt2*16 + g*4 + r at row q=li
#pragma unroll
    for (int kt2 = 0; kt2 < 4; ++kt2) {
      bf4 pk = { (__bf16)p[kt2][0], (__bf16)p[kt2][1], (__bf16)p[kt2][2], (__bf16)p[kt2][3] };
      int lchunk = (kt2 << 1) | (g >> 1);
      *(bf4*)((char*)ps[w] + li * 128 + ((lchunk ^ (li & 7)) << 4) + ((g & 1) << 3)) = pk;
    }
    asm volatile("s_waitcnt lgkmcnt(0)" ::: "memory");
    __builtin_amdgcn_sched_barrier(0);

#pragma unroll
    for (int kc2 = 0; kc2 < 2; ++kc2) {
      bh8 pf = *(const bh8*)((const char*)ps[w] + li * 128 + ((((kc2 << 2) | g) ^ (li & 7)) << 4));
#pragma unroll
      for (int dt = 0; dt < 4; ++dt) {
        int rowd = dt * 16 + li;
        bh8 vf = *(const bh8*)((const char*)vts + rowd * 128 + ((((kc2 << 2) | g) ^ (rowd & 7)) << 4));
        __builtin_amdgcn_s_setprio(1);
        ot[dt] = __builtin_amdgcn_mfma_f32_16x16x32_bf16(vf, pf, ot[dt], 0, 0, 0);
        __builtin_amdgcn_s_setprio(0);
      }
    }
  }

  const float inv = 1.0f / l_run;
  const int n = b * SEQ + q0 + w * 16 + li;
#pragma unroll
  for (int dt = 0; dt < 4; ++dt) {
    float4 o4;
    o4.x = ot[dt][0] * inv; o4.y = ot[dt][1] * inv;
    o4.z = ot[dt][2] * inv; o4.w = ot[dt][3] * inv;
    *(float4*)(attn + (size_t)n * D_MODEL + h * HD + dt * 16 + g * 4) = o4;
  }
}

// ---------------------------------------------------------------------------
// Per-token dynamic int8 quantization; writes packed pre-swizzled int8 rows.
// ---------------------------------------------------------------------------
__launch_bounds__(256)
__global__ void quant_k(const float* __restrict__ attn, unsigned* __restrict__ oqp,
                        float* __restrict__ osc)
{
  const int row = blockIdx.x, t = threadIdx.x;
  float4 v = *(const float4*)(attn + (size_t)row * D_MODEL + t * 4);
  float mx = fmaxf(fmaxf(fabsf(v.x), fabsf(v.y)), fmaxf(fabsf(v.z), fabsf(v.w)));
#pragma unroll
  for (int off = 1; off < 64; off <<= 1) mx = fmaxf(mx, __shfl_xor(mx, off));
  __shared__ float red[4];
  if ((t & 63) == 0) red[t >> 6] = mx;
  __syncthreads();
  mx = fmaxf(fmaxf(red[0], red[1]), fmaxf(red[2], red[3]));
  const float s = mx / 127.0f;
  if (t == 0) osc[row] = s;
  int q0 = (int)fminf(fmaxf(rintf(v.x / s), -127.f), 127.f);
  int q1 = (int)fminf(fmaxf(rintf(v.y / s), -127.f), 127.f);
  int q2 = (int)fminf(fmaxf(rintf(v.z / s), -127.f), 127.f);
  int q3 = (int)fminf(fmaxf(rintf(v.w / s), -127.f), 127.f);
  unsigned pk = ((unsigned)q0 & 255u) | (((unsigned)q1 & 255u) << 8) |
                (((unsigned)q2 & 255u) << 16) | (((unsigned)q3 & 255u) << 24);
  int kg = t >> 4, c = (t >> 2) & 3, b4 = t & 3, sw = (row >> 1) & 3;
  oqp[(size_t)row * 256 + kg * 16 + ((c ^ sw) << 2) + b4] = pk;
}

// ---------------------------------------------------------------------------
extern "C" void kernel_launch(void* const* d_in, const int* in_sizes, int n_in,
                              void* d_out, int out_size, void* d_ws, size_t ws_size,
                              hipStream_t stream)
{
  const int*   x   = (const int*)d_in[0];
  const float* xs  = (const float*)d_in[1];
  const int*   wq  = (const int*)d_in[2];
  const float* wqs = (const float*)d_in[3];
  const float* bq  = (const float*)d_in[4];
  const int*   wk  = (const int*)d_in[5];
  const float* wks = (const float*)d_in[6];
  const float* bk  = (const float*)d_in[7];
  const int*   wv  = (const int*)d_in[8];
  const float* wvs = (const float*)d_in[9];
  const float* bv  = (const float*)d_in[10];
  const int*   wo  = (const int*)d_in[11];
  const float* wos = (const float*)d_in[12];
  const float* bo  = (const float*)d_in[13];
  float* out = (float*)d_out;

  char* ws = (char*)d_ws;
  const size_t MB = 1024 * 1024;
  unsigned* xp  = (unsigned*)(ws);                 // 4 MB packed x
  unsigned* wqp = (unsigned*)(ws + 4 * MB);        // 1 MB each packed weights
  unsigned* wkp = (unsigned*)(ws + 5 * MB);
  unsigned* wvp = (unsigned*)(ws + 6 * MB);
  unsigned* wop = (unsigned*)(ws + 7 * MB);
  unsigned short* qhi = (unsigned short*)(ws + 8 * MB);    // 8 MB each
  unsigned short* qlo = (unsigned short*)(ws + 16 * MB);
  unsigned short* khi = (unsigned short*)(ws + 24 * MB);
  unsigned short* klo = (unsigned short*)(ws + 32 * MB);
  unsigned short* vtw = (unsigned short*)(ws + 40 * MB);
  float*          att = (float*)(ws + 48 * MB);            // 16 MB
  unsigned*       oqp = (unsigned*)(ws);                   // overlay on xp (dead)
  float*          osc = (float*)(ws + 4 * MB);             // overlay on wqp (dead)

  const float SC = 0.125f * 1.44269504088896340736f;       // (1/sqrt(hd)) * log2(e)
  dim3 blk(256);
  pack_x_k<<<dim3(4096), blk, 0, stream>>>(x, xp);
  pack_w_k<<<dim3(4096), blk, 0, stream>>>(wq, wk, wv, wo, wqp, wkp, wvp, wop);
  gemm8_k<0><<<dim3(8, 32), blk, 0, stream>>>((const signed char*)xp, (const signed char*)wqp,
                                              xs, wqs, bq, SC, 0, qhi, qlo, nullptr);
  gemm8_k<0><<<dim3(8, 32), blk, 0, stream>>>((const signed char*)xp, (const signed char*)wkp,
                                              xs, wks, bk, 1.0f, 1, khi, klo, nullptr);
  gemm8_k<2><<<dim3(32, 8), blk, 0, stream>>>((const signed char*)wvp, (const signed char*)xp,
                                              wvs, xs, bv, 1.0f, 0, vtw, nullptr, nullptr);
  attn_k<<<dim3(32, NH, 2), blk, 0, stream>>>(qhi, qlo, khi, klo, vtw, att);
  quant_k<<<dim3(4096), blk, 0, stream>>>(att, oqp, osc);
  gemm8_k<3><<<dim3(8, 32), blk, 0, stream>>>((const signed char*)oqp, (const signed char*)wop,
                                              osc, wos, bo, 1.0f, 0, nullptr, nullptr, out);
}